// Round 1
// 166.744 us; speedup vs baseline: 1.4914x; 1.4914x over previous
//
#include <hip/hip_runtime.h>
#include <math.h>

#pragma float_control(precise, on)

#define EPSF 1e-8f
#define TRI_CHUNK 128

// R23: occupancy attack.
// - ray_kernel: TRI_CHUNK 512->128 => 1024 blocks = 4 blocks/CU = 4 waves/SIMD
//   (was 1 wave/SIMD, VALUBusy 45%). Inner-loop numerics untouched
//   (R21-certified relaxed margin M=1e-5 preserved bit-exact).
// - knn_kernel: 4 waves/point (disjoint V quarters), exact top-8 merge via
//   packed unique keys. Selection + lane-0 tail arithmetic verbatim from R22
//   => bit-identical nc/v1/dfb. init_tmin folded in (block p inits its slots).

// ---------------------------------------------------------------------------
// KNN (K=8) + coarse normal. 256 threads = 4 waves per point.
// Packed key = (d2 bits << 32) | idx (ascending d2, ties -> lower index).
// Each wave scans v = tid, tid+256, ... (disjoint subsets), extracts its
// top-8 exactly; wave 0 merges the 32 unique candidates exactly.
// ---------------------------------------------------------------------------
__global__ void __launch_bounds__(256) knn_kernel(
    const float* __restrict__ x, const float* __restrict__ verts,
    const float* __restrict__ vnorm, float* __restrict__ ncw,
    float* __restrict__ v1w, float* __restrict__ dfbw,
    unsigned int* __restrict__ tmin, int N, int V) {
#pragma clang fp contract(off)
    int p = blockIdx.x;
    int tid = threadIdx.x;
    int wave = tid >> 6;
    int lane = tid & 63;
    if (p >= N) return;

    // fold init_tmin: block p owns tmin[2p], tmin[2p+1]
    if (tid < 2) tmin[2 * p + tid] = 0x7f800000u;  // +inf

    float xx = x[p * 3 + 0];
    float xy = x[p * 3 + 1];
    float xz = x[p * 3 + 2];

    unsigned long long key[8];
#pragma unroll
    for (int i = 0; i < 8; ++i) key[i] = ~0ULL;

    for (int v = tid; v < V; v += 256) {
        float dx = xx - verts[v * 3 + 0];
        float dy = xy - verts[v * 3 + 1];
        float dz = xz - verts[v * 3 + 2];
        float d2 = ((dx * dx) + (dy * dy)) + (dz * dz);
        unsigned long long k =
            (((unsigned long long)__float_as_uint(d2)) << 32) | (unsigned int)v;
        if (k < key[7]) {
            key[7] = k;
#pragma unroll
            for (int j = 7; j > 0; --j) {
                if (key[j] < key[j - 1]) {
                    unsigned long long t = key[j];
                    key[j] = key[j - 1];
                    key[j - 1] = t;
                }
            }
        }
    }

    // per-wave exact top-8 extraction (verbatim butterfly from R22)
    unsigned long long wsel[8];
#pragma unroll
    for (int j = 0; j < 8; ++j) {
        unsigned long long m = key[0];
#pragma unroll
        for (int s = 1; s < 64; s <<= 1) {
            unsigned long long o = __shfl_xor(m, s, 64);
            if (o < m) m = o;
        }
        if (key[0] == m) {
#pragma unroll
            for (int t = 0; t < 7; ++t) key[t] = key[t + 1];
            key[7] = ~0ULL;
        }
        wsel[j] = m;
    }

    // publish candidates: 4 waves x 8 keys (all unique: disjoint v subsets)
    __shared__ unsigned long long cand[32];
    if (lane == 0) {
#pragma unroll
        for (int j = 0; j < 8; ++j) cand[wave * 8 + j] = wsel[j];
    }
    __syncthreads();
    if (wave != 0) return;

    // wave 0 merges 32 candidates -> global top-8 (exact: keys unique)
    unsigned long long c0 = (lane < 32) ? cand[lane] : ~0ULL;
    unsigned long long sel[8];
#pragma unroll
    for (int j = 0; j < 8; ++j) {
        unsigned long long m = c0;
#pragma unroll
        for (int s = 1; s < 64; s <<= 1) {
            unsigned long long o = __shfl_xor(m, s, 64);
            if (o < m) m = o;
        }
        if (c0 == m) c0 = ~0ULL;
        sel[j] = m;
    }

    if (lane != 0) return;

    // lane-0 tail: verbatim from R22 (bit-identical arithmetic order)
    float invk[8];
    float nsx = 0.f, nsy = 0.f, nsz = 0.f;
#pragma unroll
    for (int j = 0; j < 8; ++j) {
        int id = (int)(sel[j] & 0xffffffffu);
        float d2 = __uint_as_float((unsigned int)(sel[j] >> 32));
        float inv = 1.0f / fmaxf(d2, EPSF);
        invk[j] = inv;
        nsx = nsx + vnorm[id * 3 + 0] * inv;
        nsy = nsy + vnorm[id * 3 + 1] * inv;
        nsz = nsz + vnorm[id * 3 + 2] * inv;
    }
    float Wsum = ((invk[0] + invk[1]) + (invk[2] + invk[3])) +
                 ((invk[4] + invk[5]) + (invk[6] + invk[7]));

    int id0 = (int)(sel[0] & 0xffffffffu);
    float v1x = verts[id0 * 3 + 0];
    float v1y = verts[id0 * 3 + 1];
    float v1z = verts[id0 * 3 + 2];

    float dxv = xx - v1x, dyv = xy - v1y, dzv = xz - v1z;
    float d2v1 = fmaxf(((dxv * dxv) + (dyv * dyv)) + (dzv * dzv), EPSF);
    float den = 0.01f * d2v1;
    float tdx = dxv / den, tdy = dyv / den, tdz = dzv / den;

    float W = Wsum + 100.0f;
    float ntx = (nsx + tdx) / W;
    float nty = (nsy + tdy) / W;
    float ntz = (nsz + tdz) / W;
    float nrm = sqrtf(((ntx * ntx) + (nty * nty)) + (ntz * ntz)) + 1e-8f;
    float ncx = ntx / nrm, ncy = nty / nrm, ncz = ntz / nrm;

    float fx = v1x - xx, fy = v1y - xy, fz = v1z - xz;
    float fn = sqrtf(((fx * fx) + (fy * fy)) + (fz * fz)) + 1e-8f;
    fx = fx / fn; fy = fy / fn; fz = fz / fn;

    ncw[p * 3 + 0] = ncx; ncw[p * 3 + 1] = ncy; ncw[p * 3 + 2] = ncz;
    v1w[p * 3 + 0] = v1x; v1w[p * 3 + 1] = v1y; v1w[p * 3 + 2] = v1z;
    dfbw[p * 3 + 0] = fx; dfbw[p * 3 + 1] = fy; dfbw[p * 3 + 2] = fz;
}

// ---------------------------------------------------------------------------
// Moller-Trumbore over triangle chunks with relaxed barycentric margin.
// thread = ray (2 per point), blockIdx.y = chunk. LDS SoA tile (broadcast).
// TRI_CHUNK=128 => 64 chunks x 16 rblocks = 1024 blocks (4/CU, 4 waves/SIMD).
// ---------------------------------------------------------------------------
__global__ void __launch_bounds__(256) ray_kernel(
    const float* __restrict__ x, const float* __restrict__ ncw,
    const float* __restrict__ dfbw, const float* __restrict__ verts,
    const int* __restrict__ faces,
    unsigned int* __restrict__ tmin, int N, int F) {
#pragma clang fp contract(off)
    const float M = 1e-5f;  // graze margin (R21-certified)
    __shared__ float sh[9][TRI_CHUNK];
    int tid = threadIdx.x;
    int cbase = blockIdx.y * TRI_CHUNK;
    int cnt = min(TRI_CHUNK, F - cbase);

    for (int j = tid; j < cnt; j += 256) {
        int fi = cbase + j;
        int f0 = faces[fi * 3 + 0];
        int f1 = faces[fi * 3 + 1];
        int f2 = faces[fi * 3 + 2];
        float t0x = verts[f0 * 3 + 0], t0y = verts[f0 * 3 + 1], t0z = verts[f0 * 3 + 2];
        float ax = verts[f1 * 3 + 0], ay = verts[f1 * 3 + 1], az = verts[f1 * 3 + 2];
        float bx = verts[f2 * 3 + 0], by = verts[f2 * 3 + 1], bz = verts[f2 * 3 + 2];
        sh[0][j] = t0x;
        sh[1][j] = t0y;
        sh[2][j] = t0z;
        sh[3][j] = ax - t0x;
        sh[4][j] = ay - t0y;
        sh[5][j] = az - t0z;
        sh[6][j] = bx - t0x;
        sh[7][j] = by - t0y;
        sh[8][j] = bz - t0z;
    }
    __syncthreads();

    int rid = blockIdx.x * 256 + tid;
    if (rid >= 2 * N) return;
    int pnt = rid >> 1;

    float ox = x[pnt * 3 + 0];
    float oy = x[pnt * 3 + 1];
    float oz = x[pnt * 3 + 2];
    float dx, dy, dz;
    if (rid & 1) {
        dx = dfbw[pnt * 3 + 0]; dy = dfbw[pnt * 3 + 1]; dz = dfbw[pnt * 3 + 2];
    } else {
        dx = -ncw[pnt * 3 + 0]; dy = -ncw[pnt * 3 + 1]; dz = -ncw[pnt * 3 + 2];
    }

    float tbest = __uint_as_float(0x7f800000u);
    for (int j = 0; j < cnt; ++j) {
        float e1x = sh[3][j], e1y = sh[4][j], e1z = sh[5][j];
        float e2x = sh[6][j], e2y = sh[7][j], e2z = sh[8][j];
        float px = (dy * e2z) - (dz * e2y);
        float py = (dz * e2x) - (dx * e2z);
        float pz = (dx * e2y) - (dy * e2x);
        float det = ((e1x * px) + (e1y * py)) + (e1z * pz);
        bool ok = fabsf(det) > EPSF;
        float inv = ok ? (1.0f / det) : 0.0f;
        float tvx = ox - sh[0][j];
        float tvy = oy - sh[1][j];
        float tvz = oz - sh[2][j];
        float u = (((tvx * px) + (tvy * py)) + (tvz * pz)) * inv;
        float qx = (tvy * e1z) - (tvz * e1y);
        float qy = (tvz * e1x) - (tvx * e1z);
        float qz = (tvx * e1y) - (tvy * e1x);
        float v = (((dx * qx) + (dy * qy)) + (dz * qz)) * inv;
        float t = (((e2x * qx) + (e2y * qy)) + (e2z * qz)) * inv;
        bool valid = ok && (u >= -M) && (v >= -M) && ((u + v) <= 1.0f + M) && (t > EPSF);
        tbest = (valid && t < tbest) ? t : tbest;
    }
    atomicMin(&tmin[rid], __float_as_uint(tbest));
}

// ---------------------------------------------------------------------------
// finalize — select xc, compute s, write fp32 outputs
// out layout: xc [0,3N) | s [3N,4N) | nc [4N,7N)
// ---------------------------------------------------------------------------
__global__ void finalize_kernel(const float* __restrict__ x,
                                const float* __restrict__ ncw,
                                const float* __restrict__ v1w,
                                const float* __restrict__ dfbw,
                                const unsigned int* __restrict__ tmin,
                                float* __restrict__ out, int N) {
#pragma clang fp contract(off)
    int p = blockIdx.x * blockDim.x + threadIdx.x;
    if (p >= N) return;
    float t1 = __uint_as_float(tmin[2 * p + 0]);
    float t2 = __uint_as_float(tmin[2 * p + 1]);
    bool h1 = t1 < __uint_as_float(0x7f800000u);
    bool h2 = t2 < __uint_as_float(0x7f800000u);

    float xx = x[p * 3 + 0], xy = x[p * 3 + 1], xz = x[p * 3 + 2];
    float ncx = ncw[p * 3 + 0], ncy = ncw[p * 3 + 1], ncz = ncw[p * 3 + 2];

    float xcx, xcy, xcz;
    if (h1) {
        xcx = xx + ((-ncx) * t1);
        xcy = xy + ((-ncy) * t1);
        xcz = xz + ((-ncz) * t1);
    } else if (h2) {
        xcx = xx + (dfbw[p * 3 + 0] * t2);
        xcy = xy + (dfbw[p * 3 + 1] * t2);
        xcz = xz + (dfbw[p * 3 + 2] * t2);
    } else {
        xcx = v1w[p * 3 + 0]; xcy = v1w[p * 3 + 1]; xcz = v1w[p * 3 + 2];
    }
    float s = (((xx - xcx) * ncx) + ((xy - xcy) * ncy)) + ((xz - xcz) * ncz);

    out[p * 3 + 0] = xcx;
    out[p * 3 + 1] = xcy;
    out[p * 3 + 2] = xcz;
    out[3 * N + p] = s;
    out[4 * N + p * 3 + 0] = ncx;
    out[4 * N + p * 3 + 1] = ncy;
    out[4 * N + p * 3 + 2] = ncz;
}

// ---------------------------------------------------------------------------
extern "C" void kernel_launch(void* const* d_in, const int* in_sizes, int n_in,
                              void* d_out, int out_size, void* d_ws, size_t ws_size,
                              hipStream_t stream) {
    const float* x     = (const float*)d_in[0];
    const float* verts = (const float*)d_in[1];
    const float* vnorm = (const float*)d_in[2];
    const int*   faces = (const int*)d_in[3];
    int N = in_sizes[0] / 3;
    int V = in_sizes[1] / 3;
    int F = in_sizes[3] / 3;

    unsigned int* tmin = (unsigned int*)d_ws;            // 2*N u32
    float* ncw  = (float*)(tmin + 2 * N);                // 3*N
    float* v1w  = ncw + 3 * N;                           // 3*N
    float* dfbw = v1w + 3 * N;                           // 3*N

    hipLaunchKernelGGL(knn_kernel, dim3(N), dim3(256), 0, stream,
                       x, verts, vnorm, ncw, v1w, dfbw, tmin, N, V);
    int chunks = (F + TRI_CHUNK - 1) / TRI_CHUNK;
    int rblocks = (2 * N + 255) / 256;
    hipLaunchKernelGGL(ray_kernel, dim3(rblocks, chunks), dim3(256), 0, stream,
                       x, ncw, dfbw, verts, faces, tmin, N, F);
    hipLaunchKernelGGL(finalize_kernel, dim3((N + 255) / 256), dim3(256), 0, stream,
                       x, ncw, v1w, dfbw, tmin, (float*)d_out, N);
}

// Round 2
// 157.943 us; speedup vs baseline: 1.5745x; 1.0557x over previous
//
#include <hip/hip_runtime.h>
#include <math.h>

#pragma float_control(precise, on)

#define EPSF 1e-8f
#define TRI_CHUNK 64

// R24: occupancy + issue-slot attack.
// - ray_kernel: TRI_CHUNK 64 => 2048 blocks = 8 blocks/CU (wave-limit fit);
//   LDS repacked 48B/tri AoS => 2x ds_read_b128 + 1x b32 (was 9x b32);
//   atomic skipped when chunk had no hit. MT numerics byte-identical
//   (R21-certified margin M=1e-5, contract off, same op order).
// - knn_kernel: parity-split dual top-8 lists per lane (A=evens, B=odds) =>
//   two independent insert chains (2x ILP on the serial compare-swap path).
//   Extraction pops min(A[0],B[0]); keys unique => exact, bit-identical
//   sel[] and all downstream outputs.

// ---------------------------------------------------------------------------
// KNN (K=8) + coarse normal. 256 threads = 4 waves per point.
// Packed key = (d2 bits << 32) | idx (ascending d2, ties -> lower index).
// ---------------------------------------------------------------------------
__global__ void __launch_bounds__(256) knn_kernel(
    const float* __restrict__ x, const float* __restrict__ verts,
    const float* __restrict__ vnorm, float* __restrict__ ncw,
    float* __restrict__ v1w, float* __restrict__ dfbw,
    unsigned int* __restrict__ tmin, int N, int V) {
#pragma clang fp contract(off)
    int p = blockIdx.x;
    int tid = threadIdx.x;
    int wave = tid >> 6;
    int lane = tid & 63;
    if (p >= N) return;

    // fold init_tmin: block p owns tmin[2p], tmin[2p+1]
    if (tid < 2) tmin[2 * p + tid] = 0x7f800000u;  // +inf

    float xx = x[p * 3 + 0];
    float xy = x[p * 3 + 1];
    float xz = x[p * 3 + 2];

    unsigned long long ka[8], kb[8];
#pragma unroll
    for (int i = 0; i < 8; ++i) { ka[i] = ~0ULL; kb[i] = ~0ULL; }

    // dual-list scan: vertex va -> list A, vertex vb = va+256 -> list B.
    // Same candidate set as a single stride-256 scan => same global top-8.
    for (int va = tid; va < V; va += 512) {
        int vb = va + 256;
        bool hasB = vb < V;

        float avx = verts[va * 3 + 0];
        float avy = verts[va * 3 + 1];
        float avz = verts[va * 3 + 2];
        float bvx = 0.f, bvy = 0.f, bvz = 0.f;
        if (hasB) {
            bvx = verts[vb * 3 + 0];
            bvy = verts[vb * 3 + 1];
            bvz = verts[vb * 3 + 2];
        }

        float dxa = xx - avx, dya = xy - avy, dza = xz - avz;
        float d2a = ((dxa * dxa) + (dya * dya)) + (dza * dza);
        unsigned long long kA =
            (((unsigned long long)__float_as_uint(d2a)) << 32) | (unsigned int)va;
        if (kA < ka[7]) {
            ka[7] = kA;
#pragma unroll
            for (int j = 7; j > 0; --j) {
                if (ka[j] < ka[j - 1]) {
                    unsigned long long t = ka[j];
                    ka[j] = ka[j - 1];
                    ka[j - 1] = t;
                }
            }
        }

        if (hasB) {
            float dxb = xx - bvx, dyb = xy - bvy, dzb = xz - bvz;
            float d2b = ((dxb * dxb) + (dyb * dyb)) + (dzb * dzb);
            unsigned long long kB =
                (((unsigned long long)__float_as_uint(d2b)) << 32) | (unsigned int)vb;
            if (kB < kb[7]) {
                kb[7] = kB;
#pragma unroll
                for (int j = 7; j > 0; --j) {
                    if (kb[j] < kb[j - 1]) {
                        unsigned long long t = kb[j];
                        kb[j] = kb[j - 1];
                        kb[j - 1] = t;
                    }
                }
            }
        }
    }

    // per-wave exact top-8 extraction over the dual lists
    unsigned long long wsel[8];
#pragma unroll
    for (int j = 0; j < 8; ++j) {
        unsigned long long c = (ka[0] < kb[0]) ? ka[0] : kb[0];
        unsigned long long m = c;
#pragma unroll
        for (int s = 1; s < 64; s <<= 1) {
            unsigned long long o = __shfl_xor(m, s, 64);
            if (o < m) m = o;
        }
        if (c == m) {  // unique keys: exactly one lane pops
            if (ka[0] == m) {
#pragma unroll
                for (int t = 0; t < 7; ++t) ka[t] = ka[t + 1];
                ka[7] = ~0ULL;
            } else {
#pragma unroll
                for (int t = 0; t < 7; ++t) kb[t] = kb[t + 1];
                kb[7] = ~0ULL;
            }
        }
        wsel[j] = m;
    }

    // publish candidates: 4 waves x 8 keys (all unique: disjoint v subsets)
    __shared__ unsigned long long cand[32];
    if (lane == 0) {
#pragma unroll
        for (int j = 0; j < 8; ++j) cand[wave * 8 + j] = wsel[j];
    }
    __syncthreads();
    if (wave != 0) return;

    // wave 0 merges 32 candidates -> global top-8 (exact: keys unique)
    unsigned long long c0 = (lane < 32) ? cand[lane] : ~0ULL;
    unsigned long long sel[8];
#pragma unroll
    for (int j = 0; j < 8; ++j) {
        unsigned long long m = c0;
#pragma unroll
        for (int s = 1; s < 64; s <<= 1) {
            unsigned long long o = __shfl_xor(m, s, 64);
            if (o < m) m = o;
        }
        if (c0 == m) c0 = ~0ULL;
        sel[j] = m;
    }

    if (lane != 0) return;

    // lane-0 tail: verbatim (bit-identical arithmetic order)
    float invk[8];
    float nsx = 0.f, nsy = 0.f, nsz = 0.f;
#pragma unroll
    for (int j = 0; j < 8; ++j) {
        int id = (int)(sel[j] & 0xffffffffu);
        float d2 = __uint_as_float((unsigned int)(sel[j] >> 32));
        float inv = 1.0f / fmaxf(d2, EPSF);
        invk[j] = inv;
        nsx = nsx + vnorm[id * 3 + 0] * inv;
        nsy = nsy + vnorm[id * 3 + 1] * inv;
        nsz = nsz + vnorm[id * 3 + 2] * inv;
    }
    float Wsum = ((invk[0] + invk[1]) + (invk[2] + invk[3])) +
                 ((invk[4] + invk[5]) + (invk[6] + invk[7]));

    int id0 = (int)(sel[0] & 0xffffffffu);
    float v1x = verts[id0 * 3 + 0];
    float v1y = verts[id0 * 3 + 1];
    float v1z = verts[id0 * 3 + 2];

    float dxv = xx - v1x, dyv = xy - v1y, dzv = xz - v1z;
    float d2v1 = fmaxf(((dxv * dxv) + (dyv * dyv)) + (dzv * dzv), EPSF);
    float den = 0.01f * d2v1;
    float tdx = dxv / den, tdy = dyv / den, tdz = dzv / den;

    float W = Wsum + 100.0f;
    float ntx = (nsx + tdx) / W;
    float nty = (nsy + tdy) / W;
    float ntz = (nsz + tdz) / W;
    float nrm = sqrtf(((ntx * ntx) + (nty * nty)) + (ntz * ntz)) + 1e-8f;
    float ncx = ntx / nrm, ncy = nty / nrm, ncz = ntz / nrm;

    float fx = v1x - xx, fy = v1y - xy, fz = v1z - xz;
    float fn = sqrtf(((fx * fx) + (fy * fy)) + (fz * fz)) + 1e-8f;
    fx = fx / fn; fy = fy / fn; fz = fz / fn;

    ncw[p * 3 + 0] = ncx; ncw[p * 3 + 1] = ncy; ncw[p * 3 + 2] = ncz;
    v1w[p * 3 + 0] = v1x; v1w[p * 3 + 1] = v1y; v1w[p * 3 + 2] = v1z;
    dfbw[p * 3 + 0] = fx; dfbw[p * 3 + 1] = fy; dfbw[p * 3 + 2] = fz;
}

// ---------------------------------------------------------------------------
// Moller-Trumbore over triangle chunks with relaxed barycentric margin.
// thread = ray (2 per point), blockIdx.y = chunk. LDS AoS 48B/tri (broadcast,
// 2x ds_read_b128 + 1x b32). TRI_CHUNK=64 => 2048 blocks = 8 blocks/CU.
// ---------------------------------------------------------------------------
__global__ void __launch_bounds__(256) ray_kernel(
    const float* __restrict__ x, const float* __restrict__ ncw,
    const float* __restrict__ dfbw, const float* __restrict__ verts,
    const int* __restrict__ faces,
    unsigned int* __restrict__ tmin, int N, int F) {
#pragma clang fp contract(off)
    const float M = 1e-5f;  // graze margin (R21-certified)
    __shared__ __align__(16) float sh[TRI_CHUNK * 12];
    int tid = threadIdx.x;
    int cbase = blockIdx.y * TRI_CHUNK;
    int cnt = min(TRI_CHUNK, F - cbase);

    for (int j = tid; j < cnt; j += 256) {
        int fi = cbase + j;
        int f0 = faces[fi * 3 + 0];
        int f1 = faces[fi * 3 + 1];
        int f2 = faces[fi * 3 + 2];
        float t0x = verts[f0 * 3 + 0], t0y = verts[f0 * 3 + 1], t0z = verts[f0 * 3 + 2];
        float ax = verts[f1 * 3 + 0], ay = verts[f1 * 3 + 1], az = verts[f1 * 3 + 2];
        float bx = verts[f2 * 3 + 0], by = verts[f2 * 3 + 1], bz = verts[f2 * 3 + 2];
        float4* s4 = (float4*)(sh + j * 12);
        s4[0] = make_float4(t0x, t0y, t0z, ax - t0x);
        s4[1] = make_float4(ay - t0y, az - t0z, bx - t0x, by - t0y);
        sh[j * 12 + 8] = bz - t0z;
    }
    __syncthreads();

    int rid = blockIdx.x * 256 + tid;
    if (rid >= 2 * N) return;
    int pnt = rid >> 1;

    float ox = x[pnt * 3 + 0];
    float oy = x[pnt * 3 + 1];
    float oz = x[pnt * 3 + 2];
    float dx, dy, dz;
    if (rid & 1) {
        dx = dfbw[pnt * 3 + 0]; dy = dfbw[pnt * 3 + 1]; dz = dfbw[pnt * 3 + 2];
    } else {
        dx = -ncw[pnt * 3 + 0]; dy = -ncw[pnt * 3 + 1]; dz = -ncw[pnt * 3 + 2];
    }

    const float INF = __uint_as_float(0x7f800000u);
    float tbest = INF;
    for (int j = 0; j < cnt; ++j) {
        const float4 A = *(const float4*)(sh + j * 12);
        const float4 B = *(const float4*)(sh + j * 12 + 4);
        const float e2z = sh[j * 12 + 8];
        float e1x = A.w, e1y = B.x, e1z = B.y;
        float e2x = B.z, e2y = B.w;
        float px = (dy * e2z) - (dz * e2y);
        float py = (dz * e2x) - (dx * e2z);
        float pz = (dx * e2y) - (dy * e2x);
        float det = ((e1x * px) + (e1y * py)) + (e1z * pz);
        bool ok = fabsf(det) > EPSF;
        float inv = ok ? (1.0f / det) : 0.0f;
        float tvx = ox - A.x;
        float tvy = oy - A.y;
        float tvz = oz - A.z;
        float u = (((tvx * px) + (tvy * py)) + (tvz * pz)) * inv;
        float qx = (tvy * e1z) - (tvz * e1y);
        float qy = (tvz * e1x) - (tvx * e1z);
        float qz = (tvx * e1y) - (tvy * e1x);
        float v = (((dx * qx) + (dy * qy)) + (dz * qz)) * inv;
        float t = (((e2x * qx) + (e2y * qy)) + (e2z * qz)) * inv;
        bool valid = ok && (u >= -M) && (v >= -M) && ((u + v) <= 1.0f + M) && (t > EPSF);
        tbest = (valid && t < tbest) ? t : tbest;
    }
    if (tbest < INF) atomicMin(&tmin[rid], __float_as_uint(tbest));
}

// ---------------------------------------------------------------------------
// finalize — select xc, compute s, write fp32 outputs
// out layout: xc [0,3N) | s [3N,4N) | nc [4N,7N)
// ---------------------------------------------------------------------------
__global__ void finalize_kernel(const float* __restrict__ x,
                                const float* __restrict__ ncw,
                                const float* __restrict__ v1w,
                                const float* __restrict__ dfbw,
                                const unsigned int* __restrict__ tmin,
                                float* __restrict__ out, int N) {
#pragma clang fp contract(off)
    int p = blockIdx.x * blockDim.x + threadIdx.x;
    if (p >= N) return;
    float t1 = __uint_as_float(tmin[2 * p + 0]);
    float t2 = __uint_as_float(tmin[2 * p + 1]);
    bool h1 = t1 < __uint_as_float(0x7f800000u);
    bool h2 = t2 < __uint_as_float(0x7f800000u);

    float xx = x[p * 3 + 0], xy = x[p * 3 + 1], xz = x[p * 3 + 2];
    float ncx = ncw[p * 3 + 0], ncy = ncw[p * 3 + 1], ncz = ncw[p * 3 + 2];

    float xcx, xcy, xcz;
    if (h1) {
        xcx = xx + ((-ncx) * t1);
        xcy = xy + ((-ncy) * t1);
        xcz = xz + ((-ncz) * t1);
    } else if (h2) {
        xcx = xx + (dfbw[p * 3 + 0] * t2);
        xcy = xy + (dfbw[p * 3 + 1] * t2);
        xcz = xz + (dfbw[p * 3 + 2] * t2);
    } else {
        xcx = v1w[p * 3 + 0]; xcy = v1w[p * 3 + 1]; xcz = v1w[p * 3 + 2];
    }
    float s = (((xx - xcx) * ncx) + ((xy - xcy) * ncy)) + ((xz - xcz) * ncz);

    out[p * 3 + 0] = xcx;
    out[p * 3 + 1] = xcy;
    out[p * 3 + 2] = xcz;
    out[3 * N + p] = s;
    out[4 * N + p * 3 + 0] = ncx;
    out[4 * N + p * 3 + 1] = ncy;
    out[4 * N + p * 3 + 2] = ncz;
}

// ---------------------------------------------------------------------------
extern "C" void kernel_launch(void* const* d_in, const int* in_sizes, int n_in,
                              void* d_out, int out_size, void* d_ws, size_t ws_size,
                              hipStream_t stream) {
    const float* x     = (const float*)d_in[0];
    const float* verts = (const float*)d_in[1];
    const float* vnorm = (const float*)d_in[2];
    const int*   faces = (const int*)d_in[3];
    int N = in_sizes[0] / 3;
    int V = in_sizes[1] / 3;
    int F = in_sizes[3] / 3;

    unsigned int* tmin = (unsigned int*)d_ws;            // 2*N u32
    float* ncw  = (float*)(tmin + 2 * N);                // 3*N
    float* v1w  = ncw + 3 * N;                           // 3*N
    float* dfbw = v1w + 3 * N;                           // 3*N

    hipLaunchKernelGGL(knn_kernel, dim3(N), dim3(256), 0, stream,
                       x, verts, vnorm, ncw, v1w, dfbw, tmin, N, V);
    int chunks = (F + TRI_CHUNK - 1) / TRI_CHUNK;
    int rblocks = (2 * N + 255) / 256;
    hipLaunchKernelGGL(ray_kernel, dim3(rblocks, chunks), dim3(256), 0, stream,
                       x, ncw, dfbw, verts, faces, tmin, N, F);
    hipLaunchKernelGGL(finalize_kernel, dim3((N + 255) / 256), dim3(256), 0, stream,
                       x, ncw, v1w, dfbw, tmin, (float*)d_out, N);
}

// Round 4
// 145.368 us; speedup vs baseline: 1.7107x; 1.0865x over previous
//
#include <hip/hip_runtime.h>
#include <math.h>

#pragma float_control(precise, on)

#define EPSF 1e-8f
#define TRI_CHUNK 32

// R26 = R25 resubmit (infra failure last round; kernel never ran).
// Only delta: __launch_bounds__(256,8) -> (256,4) to rule out a
// register-allocator hard-failure on the waves/EU demand. Occupancy target
// (8 blocks/CU) is still reached via actual VGPR count (~45 < 64).
//
// R25: ray-pair fusion.
// - ray_kernel: one thread per POINT, evaluating both rays (-nc, dfb) per
//   triangle. Shared-origin terms (tvec, qvec, dot(e2,qvec)) computed once
//   (they were ray-independent values already => bit-identical); per-ray
//   pvec/det/inv/u/v/t and R21-certified relaxed test (M=1e-5) verbatim.
//   TRI_CHUNK 32 => 8 x 256 = 2048 blocks (8/CU backlog), staging traffic
//   halved (8 point-blocks per chunk, was 16 ray-blocks).
// - knn_kernel / finalize: unchanged from R24.

// ---------------------------------------------------------------------------
// KNN (K=8) + coarse normal. 256 threads = 4 waves per point.
// Packed key = (d2 bits << 32) | idx (ascending d2, ties -> lower index).
// ---------------------------------------------------------------------------
__global__ void __launch_bounds__(256) knn_kernel(
    const float* __restrict__ x, const float* __restrict__ verts,
    const float* __restrict__ vnorm, float* __restrict__ ncw,
    float* __restrict__ v1w, float* __restrict__ dfbw,
    unsigned int* __restrict__ tmin, int N, int V) {
#pragma clang fp contract(off)
    int p = blockIdx.x;
    int tid = threadIdx.x;
    int wave = tid >> 6;
    int lane = tid & 63;
    if (p >= N) return;

    // fold init_tmin: block p owns tmin[2p], tmin[2p+1]
    if (tid < 2) tmin[2 * p + tid] = 0x7f800000u;  // +inf

    float xx = x[p * 3 + 0];
    float xy = x[p * 3 + 1];
    float xz = x[p * 3 + 2];

    unsigned long long ka[8], kb[8];
#pragma unroll
    for (int i = 0; i < 8; ++i) { ka[i] = ~0ULL; kb[i] = ~0ULL; }

    // dual-list scan: vertex va -> list A, vertex vb = va+256 -> list B.
    for (int va = tid; va < V; va += 512) {
        int vb = va + 256;
        bool hasB = vb < V;

        float avx = verts[va * 3 + 0];
        float avy = verts[va * 3 + 1];
        float avz = verts[va * 3 + 2];
        float bvx = 0.f, bvy = 0.f, bvz = 0.f;
        if (hasB) {
            bvx = verts[vb * 3 + 0];
            bvy = verts[vb * 3 + 1];
            bvz = verts[vb * 3 + 2];
        }

        float dxa = xx - avx, dya = xy - avy, dza = xz - avz;
        float d2a = ((dxa * dxa) + (dya * dya)) + (dza * dza);
        unsigned long long kA =
            (((unsigned long long)__float_as_uint(d2a)) << 32) | (unsigned int)va;
        if (kA < ka[7]) {
            ka[7] = kA;
#pragma unroll
            for (int j = 7; j > 0; --j) {
                if (ka[j] < ka[j - 1]) {
                    unsigned long long t = ka[j];
                    ka[j] = ka[j - 1];
                    ka[j - 1] = t;
                }
            }
        }

        if (hasB) {
            float dxb = xx - bvx, dyb = xy - bvy, dzb = xz - bvz;
            float d2b = ((dxb * dxb) + (dyb * dyb)) + (dzb * dzb);
            unsigned long long kB =
                (((unsigned long long)__float_as_uint(d2b)) << 32) | (unsigned int)vb;
            if (kB < kb[7]) {
                kb[7] = kB;
#pragma unroll
                for (int j = 7; j > 0; --j) {
                    if (kb[j] < kb[j - 1]) {
                        unsigned long long t = kb[j];
                        kb[j] = kb[j - 1];
                        kb[j - 1] = t;
                    }
                }
            }
        }
    }

    // per-wave exact top-8 extraction over the dual lists
    unsigned long long wsel[8];
#pragma unroll
    for (int j = 0; j < 8; ++j) {
        unsigned long long c = (ka[0] < kb[0]) ? ka[0] : kb[0];
        unsigned long long m = c;
#pragma unroll
        for (int s = 1; s < 64; s <<= 1) {
            unsigned long long o = __shfl_xor(m, s, 64);
            if (o < m) m = o;
        }
        if (c == m) {  // unique keys: exactly one lane pops
            if (ka[0] == m) {
#pragma unroll
                for (int t = 0; t < 7; ++t) ka[t] = ka[t + 1];
                ka[7] = ~0ULL;
            } else {
#pragma unroll
                for (int t = 0; t < 7; ++t) kb[t] = kb[t + 1];
                kb[7] = ~0ULL;
            }
        }
        wsel[j] = m;
    }

    // publish candidates: 4 waves x 8 keys (all unique: disjoint v subsets)
    __shared__ unsigned long long cand[32];
    if (lane == 0) {
#pragma unroll
        for (int j = 0; j < 8; ++j) cand[wave * 8 + j] = wsel[j];
    }
    __syncthreads();
    if (wave != 0) return;

    // wave 0 merges 32 candidates -> global top-8 (exact: keys unique)
    unsigned long long c0 = (lane < 32) ? cand[lane] : ~0ULL;
    unsigned long long sel[8];
#pragma unroll
    for (int j = 0; j < 8; ++j) {
        unsigned long long m = c0;
#pragma unroll
        for (int s = 1; s < 64; s <<= 1) {
            unsigned long long o = __shfl_xor(m, s, 64);
            if (o < m) m = o;
        }
        if (c0 == m) c0 = ~0ULL;
        sel[j] = m;
    }

    if (lane != 0) return;

    // lane-0 tail: verbatim (bit-identical arithmetic order)
    float invk[8];
    float nsx = 0.f, nsy = 0.f, nsz = 0.f;
#pragma unroll
    for (int j = 0; j < 8; ++j) {
        int id = (int)(sel[j] & 0xffffffffu);
        float d2 = __uint_as_float((unsigned int)(sel[j] >> 32));
        float inv = 1.0f / fmaxf(d2, EPSF);
        invk[j] = inv;
        nsx = nsx + vnorm[id * 3 + 0] * inv;
        nsy = nsy + vnorm[id * 3 + 1] * inv;
        nsz = nsz + vnorm[id * 3 + 2] * inv;
    }
    float Wsum = ((invk[0] + invk[1]) + (invk[2] + invk[3])) +
                 ((invk[4] + invk[5]) + (invk[6] + invk[7]));

    int id0 = (int)(sel[0] & 0xffffffffu);
    float v1x = verts[id0 * 3 + 0];
    float v1y = verts[id0 * 3 + 1];
    float v1z = verts[id0 * 3 + 2];

    float dxv = xx - v1x, dyv = xy - v1y, dzv = xz - v1z;
    float d2v1 = fmaxf(((dxv * dxv) + (dyv * dyv)) + (dzv * dzv), EPSF);
    float den = 0.01f * d2v1;
    float tdx = dxv / den, tdy = dyv / den, tdz = dzv / den;

    float W = Wsum + 100.0f;
    float ntx = (nsx + tdx) / W;
    float nty = (nsy + tdy) / W;
    float ntz = (nsz + tdz) / W;
    float nrm = sqrtf(((ntx * ntx) + (nty * nty)) + (ntz * ntz)) + 1e-8f;
    float ncx = ntx / nrm, ncy = nty / nrm, ncz = ntz / nrm;

    float fx = v1x - xx, fy = v1y - xy, fz = v1z - xz;
    float fn = sqrtf(((fx * fx) + (fy * fy)) + (fz * fz)) + 1e-8f;
    fx = fx / fn; fy = fy / fn; fz = fz / fn;

    ncw[p * 3 + 0] = ncx; ncw[p * 3 + 1] = ncy; ncw[p * 3 + 2] = ncz;
    v1w[p * 3 + 0] = v1x; v1w[p * 3 + 1] = v1y; v1w[p * 3 + 2] = v1z;
    dfbw[p * 3 + 0] = fx; dfbw[p * 3 + 1] = fy; dfbw[p * 3 + 2] = fz;
}

// ---------------------------------------------------------------------------
// Moller-Trumbore, ray-pair fused: thread = point, both rays per iteration.
// blockIdx.y = chunk of TRI_CHUNK tris staged in LDS (AoS 48B/tri).
// Shared-origin terms (tvec, qvec, dot(e2,qvec)) computed once per pair —
// identical values/op-order as the per-ray version => bit-exact.
// ---------------------------------------------------------------------------
__global__ void __launch_bounds__(256, 4) ray_kernel(
    const float* __restrict__ x, const float* __restrict__ ncw,
    const float* __restrict__ dfbw, const float* __restrict__ verts,
    const int* __restrict__ faces,
    unsigned int* __restrict__ tmin, int N, int F) {
#pragma clang fp contract(off)
    const float M = 1e-5f;  // graze margin (R21-certified)
    __shared__ __align__(16) float sh[TRI_CHUNK * 12];
    int tid = threadIdx.x;
    int cbase = blockIdx.y * TRI_CHUNK;
    int cnt = min(TRI_CHUNK, F - cbase);

    for (int j = tid; j < cnt; j += 256) {
        int fi = cbase + j;
        int f0 = faces[fi * 3 + 0];
        int f1 = faces[fi * 3 + 1];
        int f2 = faces[fi * 3 + 2];
        float t0x = verts[f0 * 3 + 0], t0y = verts[f0 * 3 + 1], t0z = verts[f0 * 3 + 2];
        float ax = verts[f1 * 3 + 0], ay = verts[f1 * 3 + 1], az = verts[f1 * 3 + 2];
        float bx = verts[f2 * 3 + 0], by = verts[f2 * 3 + 1], bz = verts[f2 * 3 + 2];
        float4* s4 = (float4*)(sh + j * 12);
        s4[0] = make_float4(t0x, t0y, t0z, ax - t0x);
        s4[1] = make_float4(ay - t0y, az - t0z, bx - t0x, by - t0y);
        sh[j * 12 + 8] = bz - t0z;
    }
    __syncthreads();

    int pnt = blockIdx.x * 256 + tid;
    if (pnt >= N) return;

    float ox = x[pnt * 3 + 0];
    float oy = x[pnt * 3 + 1];
    float oz = x[pnt * 3 + 2];
    // ray a = -nc (rid even), ray b = dfb (rid odd)
    float dax = -ncw[pnt * 3 + 0], day = -ncw[pnt * 3 + 1], daz = -ncw[pnt * 3 + 2];
    float dbx = dfbw[pnt * 3 + 0], dby = dfbw[pnt * 3 + 1], dbz = dfbw[pnt * 3 + 2];

    const float INF = __uint_as_float(0x7f800000u);
    float tba = INF, tbb = INF;
    for (int j = 0; j < cnt; ++j) {
        const float4 A = *(const float4*)(sh + j * 12);
        const float4 B = *(const float4*)(sh + j * 12 + 4);
        const float e2z = sh[j * 12 + 8];
        float e1x = A.w, e1y = B.x, e1z = B.y;
        float e2x = B.z, e2y = B.w;

        // shared-origin terms (ray-independent, identical op order)
        float tvx = ox - A.x;
        float tvy = oy - A.y;
        float tvz = oz - A.z;
        float qx = (tvy * e1z) - (tvz * e1y);
        float qy = (tvz * e1x) - (tvx * e1z);
        float qz = (tvx * e1y) - (tvy * e1x);
        float tq = ((e2x * qx) + (e2y * qy)) + (e2z * qz);

        // ray a
        {
            float px = (day * e2z) - (daz * e2y);
            float py = (daz * e2x) - (dax * e2z);
            float pz = (dax * e2y) - (day * e2x);
            float det = ((e1x * px) + (e1y * py)) + (e1z * pz);
            bool ok = fabsf(det) > EPSF;
            float inv = ok ? (1.0f / det) : 0.0f;
            float u = (((tvx * px) + (tvy * py)) + (tvz * pz)) * inv;
            float v = (((dax * qx) + (day * qy)) + (daz * qz)) * inv;
            float t = tq * inv;
            bool valid = ok && (u >= -M) && (v >= -M) && ((u + v) <= 1.0f + M) && (t > EPSF);
            tba = (valid && t < tba) ? t : tba;
        }
        // ray b
        {
            float px = (dby * e2z) - (dbz * e2y);
            float py = (dbz * e2x) - (dbx * e2z);
            float pz = (dbx * e2y) - (dby * e2x);
            float det = ((e1x * px) + (e1y * py)) + (e1z * pz);
            bool ok = fabsf(det) > EPSF;
            float inv = ok ? (1.0f / det) : 0.0f;
            float u = (((tvx * px) + (tvy * py)) + (tvz * pz)) * inv;
            float v = (((dbx * qx) + (dby * qy)) + (dbz * qz)) * inv;
            float t = tq * inv;
            bool valid = ok && (u >= -M) && (v >= -M) && ((u + v) <= 1.0f + M) && (t > EPSF);
            tbb = (valid && t < tbb) ? t : tbb;
        }
    }
    if (tba < INF) atomicMin(&tmin[2 * pnt + 0], __float_as_uint(tba));
    if (tbb < INF) atomicMin(&tmin[2 * pnt + 1], __float_as_uint(tbb));
}

// ---------------------------------------------------------------------------
// finalize — select xc, compute s, write fp32 outputs
// out layout: xc [0,3N) | s [3N,4N) | nc [4N,7N)
// ---------------------------------------------------------------------------
__global__ void finalize_kernel(const float* __restrict__ x,
                                const float* __restrict__ ncw,
                                const float* __restrict__ v1w,
                                const float* __restrict__ dfbw,
                                const unsigned int* __restrict__ tmin,
                                float* __restrict__ out, int N) {
#pragma clang fp contract(off)
    int p = blockIdx.x * blockDim.x + threadIdx.x;
    if (p >= N) return;
    float t1 = __uint_as_float(tmin[2 * p + 0]);
    float t2 = __uint_as_float(tmin[2 * p + 1]);
    bool h1 = t1 < __uint_as_float(0x7f800000u);
    bool h2 = t2 < __uint_as_float(0x7f800000u);

    float xx = x[p * 3 + 0], xy = x[p * 3 + 1], xz = x[p * 3 + 2];
    float ncx = ncw[p * 3 + 0], ncy = ncw[p * 3 + 1], ncz = ncw[p * 3 + 2];

    float xcx, xcy, xcz;
    if (h1) {
        xcx = xx + ((-ncx) * t1);
        xcy = xy + ((-ncy) * t1);
        xcz = xz + ((-ncz) * t1);
    } else if (h2) {
        xcx = xx + (dfbw[p * 3 + 0] * t2);
        xcy = xy + (dfbw[p * 3 + 1] * t2);
        xcz = xz + (dfbw[p * 3 + 2] * t2);
    } else {
        xcx = v1w[p * 3 + 0]; xcy = v1w[p * 3 + 1]; xcz = v1w[p * 3 + 2];
    }
    float s = (((xx - xcx) * ncx) + ((xy - xcy) * ncy)) + ((xz - xcz) * ncz);

    out[p * 3 + 0] = xcx;
    out[p * 3 + 1] = xcy;
    out[p * 3 + 2] = xcz;
    out[3 * N + p] = s;
    out[4 * N + p * 3 + 0] = ncx;
    out[4 * N + p * 3 + 1] = ncy;
    out[4 * N + p * 3 + 2] = ncz;
}

// ---------------------------------------------------------------------------
extern "C" void kernel_launch(void* const* d_in, const int* in_sizes, int n_in,
                              void* d_out, int out_size, void* d_ws, size_t ws_size,
                              hipStream_t stream) {
    const float* x     = (const float*)d_in[0];
    const float* verts = (const float*)d_in[1];
    const float* vnorm = (const float*)d_in[2];
    const int*   faces = (const int*)d_in[3];
    int N = in_sizes[0] / 3;
    int V = in_sizes[1] / 3;
    int F = in_sizes[3] / 3;

    unsigned int* tmin = (unsigned int*)d_ws;            // 2*N u32
    float* ncw  = (float*)(tmin + 2 * N);                // 3*N
    float* v1w  = ncw + 3 * N;                           // 3*N
    float* dfbw = v1w + 3 * N;                           // 3*N

    hipLaunchKernelGGL(knn_kernel, dim3(N), dim3(256), 0, stream,
                       x, verts, vnorm, ncw, v1w, dfbw, tmin, N, V);
    int chunks = (F + TRI_CHUNK - 1) / TRI_CHUNK;
    int pblocks = (N + 255) / 256;
    hipLaunchKernelGGL(ray_kernel, dim3(pblocks, chunks), dim3(256), 0, stream,
                       x, ncw, dfbw, verts, faces, tmin, N, F);
    hipLaunchKernelGGL(finalize_kernel, dim3((N + 255) / 256), dim3(256), 0, stream,
                       x, ncw, v1w, dfbw, tmin, (float*)d_out, N);
}